// Round 1
// baseline (192.083 us; speedup 1.0000x reference)
//
#include <hip/hip_runtime.h>

#define BB 8
#define CC 7
#define HH 512
#define WW 512
#define HW (HH*WW)

// ws layout:
//   [0, 224)   : 28 doubles of accumulators
//                 [0]=focal_sum [1]=bce_sum [2..8]=sumP [9..15]=inter [16..22]=cnt [23..27]=topo_num
//   [256, 256+B*HW)        : boundary mask (u8, 7 bits per pixel)
//   [256+B*HW, 256+2*B*HW) : horizontally-ORed mask (u8)

// ---------------------------------------------------------------------------
// Pass 1: per-pixel 7-bit boundary mask from targets.
// boundary_c = |lap(onehot_c)| > 0 with zero padding.
// For c==t(center): lap = s_c - 4  -> nonzero iff NOT (4 in-bounds neighbors all == c)
// For c!=t(center): lap = s_c      -> nonzero iff some in-bounds neighbor == c
__global__ __launch_bounds__(256) void bmask_kernel(const int* __restrict__ tgt,
                                                    unsigned char* __restrict__ mask) {
    int idx = blockIdx.x * 256 + threadIdx.x;
    if (idx >= BB * HW) return;
    int x = idx & (WW - 1);
    int y = (idx >> 9) & (HH - 1);
    int t = tgt[idx];
    unsigned orm = 0;
    int nfirst = -1;
    int same = 1;
    int ninb = 0;
    if (y > 0)      { int tn = tgt[idx - WW]; orm |= 1u << tn; if (nfirst < 0) nfirst = tn; else same &= (tn == nfirst); ninb++; }
    if (y < HH - 1) { int tn = tgt[idx + WW]; orm |= 1u << tn; if (nfirst < 0) nfirst = tn; else same &= (tn == nfirst); ninb++; }
    if (x > 0)      { int tn = tgt[idx - 1];  orm |= 1u << tn; if (nfirst < 0) nfirst = tn; else same &= (tn == nfirst); ninb++; }
    if (x < WW - 1) { int tn = tgt[idx + 1];  orm |= 1u << tn; if (nfirst < 0) nfirst = tn; else same &= (tn == nfirst); ninb++; }
    unsigned andm = (ninb == 4 && same) ? (1u << nfirst) : 0u;
    unsigned cbit = 1u << t;
    unsigned bits = (orm & ~cbit) | (cbit & ~andm);
    mask[idx] = (unsigned char)bits;
}

// ---------------------------------------------------------------------------
// Pass 2: horizontal 5-wide OR (zero padding).
__global__ __launch_bounds__(256) void hor_kernel(const unsigned char* __restrict__ mask,
                                                  unsigned char* __restrict__ hmask) {
    int idx = blockIdx.x * 256 + threadIdx.x;
    if (idx >= BB * HW) return;
    int x = idx & (WW - 1);
    unsigned m = 0;
#pragma unroll
    for (int dx = -2; dx <= 2; dx++) {
        int xx = x + dx;
        if ((unsigned)xx < WW) m |= mask[idx + dx];
    }
    hmask[idx] = (unsigned char)m;
}

// ---------------------------------------------------------------------------
// Pass 3: fused main kernel. One block = 32x32 output pixels of one image.
// Phase A: softmax for 34x34 halo tile into LDS (probs, targets).
// Phase B: per-pixel focal/dice/bce/topo accumulation.
// Phase C: block reduce + 28 double atomics.
__global__ __launch_bounds__(256) void main_kernel(const float* __restrict__ logits,
                                                   const int* __restrict__ tgt,
                                                   const float* __restrict__ cw,
                                                   const unsigned char* __restrict__ hmask,
                                                   double* __restrict__ acc) {
    __shared__ float sp[1156 * 7];          // probs for halo tile
    __shared__ unsigned char st[1160];      // targets for halo tile (255 = OOB)
    __shared__ float sw[8];                 // class weights
    __shared__ float sred[4 * 28];          // cross-wave reduction

    const int tid = threadIdx.x;
    const int b = blockIdx.z;
    const int x0 = blockIdx.x * 32 - 1;
    const int y0 = blockIdx.y * 32 - 1;
    if (tid < 7) sw[tid] = cw[tid];

    const float* lg = logits + (size_t)b * CC * HW;
    const int* tg = tgt + (size_t)b * HW;

    // ---- Phase A ----
    for (int p = tid; p < 1156; p += 256) {
        int iy = p / 34;
        int ix = p - iy * 34;
        int y = y0 + iy, x = x0 + ix;
        float pr[7];
        int tv = 255;
        if ((unsigned)x < WW && (unsigned)y < HH) {
            const float* lp = lg + y * WW + x;
            float l[7];
#pragma unroll
            for (int c = 0; c < 7; c++) l[c] = lp[c * HW];
            float m = l[0];
#pragma unroll
            for (int c = 1; c < 7; c++) m = fmaxf(m, l[c]);
            float se = 0.f;
#pragma unroll
            for (int c = 0; c < 7; c++) { pr[c] = __expf(l[c] - m); se += pr[c]; }
            float inv = 1.0f / se;
#pragma unroll
            for (int c = 0; c < 7; c++) pr[c] *= inv;
            tv = tg[y * WW + x];
        } else {
#pragma unroll
            for (int c = 0; c < 7; c++) pr[c] = 0.f;
        }
#pragma unroll
        for (int c = 0; c < 7; c++) sp[p * 7 + c] = pr[c];
        st[p] = (unsigned char)tv;
    }
    __syncthreads();

    // ---- Phase B ----
    float accF = 0.f, accB = 0.f;
    float sumP[7] = {0, 0, 0, 0, 0, 0, 0};
    float inter[7] = {0, 0, 0, 0, 0, 0, 0};
    float cnt[7] = {0, 0, 0, 0, 0, 0, 0};
    float num[5] = {0, 0, 0, 0, 0};
    const int gy_base = blockIdx.y * 32;
    const int gx_base = blockIdx.x * 32;
    const unsigned char* hm = hmask + (size_t)b * HW;

#pragma unroll
    for (int k = 0; k < 4; k++) {
        int p = tid + k * 256;
        int cy = p >> 5, cx = p & 31;
        int hp = (cy + 1) * 34 + (cx + 1);
        int t = st[hp];
        float pr[7];
#pragma unroll
        for (int c = 0; c < 7; c++) pr[c] = sp[hp * 7 + c];

        // focal
        float p_t = sp[hp * 7 + t];    // dynamic LDS index (stays in LDS, no scratch)
        float wt = sw[t];
        float nll = -__logf(p_t);
        float ce = wt * nll;
        float ptv = __expf(-ce);
        float om = 1.0f - ptv;
        accF += om * om * ce;

        // boundary weight: vertical 5-OR of hmask
        int gy = gy_base + cy, gx = gx_base + cx;
        unsigned rm = 0;
#pragma unroll
        for (int dy = -2; dy <= 2; dy++) {
            int yy = gy + dy;
            if ((unsigned)yy < HH) rm |= hm[yy * WW + gx];
        }

#pragma unroll
        for (int c = 0; c < 7; c++) {
            float prc = pr[c];
            sumP[c] += prc;
            bool is = (c == t);
            if (is) { inter[c] += prc; cnt[c] += 1.0f; }
            float bw = 1.0f + 4.0f * (float)((rm >> c) & 1u);
            float bce = is ? -__logf(prc + 1e-7f) : -__logf(1.0f - prc + 1e-7f);
            accB += bw * bce;
        }

        // topo: 3x3 avg of (probs - onehot) for channel t if t in [2,7)
#pragma unroll
        for (int c = 2; c < 7; c++) {
            if (t == c) {
                float s = 0.f;
#pragma unroll
                for (int dy = -1; dy <= 1; dy++) {
#pragma unroll
                    for (int dx = -1; dx <= 1; dx++) {
                        int np = hp + dy * 34 + dx;
                        s += sp[np * 7 + c] - ((st[np] == c) ? 1.0f : 0.0f);
                    }
                }
                num[c - 2] += fabsf(s * (1.0f / 9.0f));
            }
        }
    }

    // ---- Phase C ----
    float vals[28];
    vals[0] = accF;
    vals[1] = accB;
#pragma unroll
    for (int c = 0; c < 7; c++) {
        vals[2 + c] = sumP[c];
        vals[9 + c] = inter[c];
        vals[16 + c] = cnt[c];
    }
#pragma unroll
    for (int j = 0; j < 5; j++) vals[23 + j] = num[j];

    int lane = tid & 63, wid = tid >> 6;
#pragma unroll
    for (int i = 0; i < 28; i++) {
        float v = vals[i];
#pragma unroll
        for (int o = 32; o > 0; o >>= 1) v += __shfl_down(v, o, 64);
        if (lane == 0) sred[wid * 28 + i] = v;
    }
    __syncthreads();
    if (tid < 28) {
        float s = sred[tid] + sred[28 + tid] + sred[56 + tid] + sred[84 + tid];
        atomicAdd(&acc[tid], (double)s);
    }
}

// ---------------------------------------------------------------------------
// Pass 4: finalize scalar.
__global__ void finalize_kernel(const double* __restrict__ acc, float* __restrict__ out) {
    if (threadIdx.x == 0 && blockIdx.x == 0) {
        double focal = acc[0] / (double)((size_t)BB * HW);
        double bound = acc[1] / (double)((size_t)BB * CC * HW);
        double dice = 0.0;
#pragma unroll
        for (int c = 0; c < 7; c++) {
            double uni = acc[2 + c] + acc[16 + c];
            double in2 = acc[9 + c];
            dice += 1.0 - (2.0 * in2 + 1e-6) / (uni + 1e-6);
        }
        dice *= (1.0 / 7.0);
        double topo = 0.0;
#pragma unroll
        for (int j = 0; j < 5; j++) {
            double ms = acc[18 + j];   // cnt[2+j]
            double nm = acc[23 + j];
            topo += (ms >= 1.0) ? nm / fmax(ms, 1.0) : 0.0;
        }
        topo *= (1.0 / 5.0);
        out[0] = (float)(0.3 * focal + 0.3 * dice + 0.2 * bound + 0.2 * topo);
    }
}

extern "C" void kernel_launch(void* const* d_in, const int* in_sizes, int n_in,
                              void* d_out, int out_size, void* d_ws, size_t ws_size,
                              hipStream_t stream) {
    const float* logits = (const float*)d_in[0];
    const int* tgt = (const int*)d_in[1];
    const float* cw = (const float*)d_in[2];
    float* out = (float*)d_out;

    char* ws = (char*)d_ws;
    double* acc = (double*)ws;
    unsigned char* mask = (unsigned char*)(ws + 256);
    unsigned char* hmask = mask + (size_t)BB * HW;

    hipMemsetAsync(acc, 0, 28 * sizeof(double), stream);

    int npix = BB * HW;
    bmask_kernel<<<(npix + 255) / 256, 256, 0, stream>>>(tgt, mask);
    hor_kernel<<<(npix + 255) / 256, 256, 0, stream>>>(mask, hmask);

    dim3 grid(WW / 32, HH / 32, BB);
    main_kernel<<<grid, 256, 0, stream>>>(logits, tgt, cw, hmask, acc);
    finalize_kernel<<<1, 64, 0, stream>>>(acc, out);
}